// Round 16
// baseline (199.359 us; speedup 1.0000x reference)
//
#include <hip/hip_runtime.h>

typedef __bf16 bx8 __attribute__((ext_vector_type(8)));
typedef __bf16 bx4 __attribute__((ext_vector_type(4)));
typedef float  fx4 __attribute__((ext_vector_type(4)));
typedef unsigned long long u64;
typedef unsigned char u8;

#define B_   4
#define S_   2048
#define DIN  1024
#define DH   1024

#define MB ((size_t)1 << 20)
// workspace layout (bytes)
#define WS_A1 ((size_t)0)          // seq1 bf16, 16MB  (stacked with A2; aliased by Pu later)
#define WS_A2 ((size_t)16*MB)      // seq2 bf16, 16MB  (A1..A2 contiguous = 16384x1024)
#define WS_PU ((size_t)0)          // exp-scores bf16, 32MB (after QKV done)
#define WS_WQ ((size_t)32*MB)      // WQ,WK,WV bf16 contiguous 3072x1024 (6MB)
#define WS_BM ((size_t)38*MB)      // mask bitmask 2MB (bytes: bit j of byte i = mask[8i+j])
#define WS_Q  ((size_t)40*MB)      // q bf16 [B*S, DH] 16MB
#define WS_K  ((size_t)56*MB)      // k bf16 [B*S, DH] 16MB
#define WS_VT ((size_t)72*MB)      // v^T bf16 [B, DH, S] 16MB
#define WS_CS ((size_t)88*MB)      // colsum fp32 [B, S] 32KB

// ---------------------------------------------------------------- fused prep:
// blocks [0,8192): seq1/seq2 f32->bf16; [8192,9728): Wq/Wk/Wv f32->bf16;
// [9728,10752): mask int32 -> byte-bitmask; block 10752: zero cs.
__global__ void prep(const float* __restrict__ s1, const float* __restrict__ s2,
                     const float* __restrict__ wq, const float* __restrict__ wk,
                     const float* __restrict__ wv, const int* __restrict__ mask,
                     __bf16* __restrict__ o1, __bf16* __restrict__ o2,
                     __bf16* __restrict__ ow, u8* __restrict__ bm,
                     float* __restrict__ cs) {
  const int b = blockIdx.x;
  if (b >= 10752) {
#pragma unroll
    for (int j = 0; j < 8; j++)
      ((fx4*)cs)[threadIdx.x * 8 + j] = fx4{0.f, 0.f, 0.f, 0.f};
    return;
  }
  if (b < 9728) {
    const float* in;
    __bf16* out;
    size_t i;
    if (b < 8192) {
      in  = b < 4096 ? s1 : s2;
      out = b < 4096 ? o1 : o2;
      i = (size_t)(b & 4095) * 256 + threadIdx.x;
    } else {
      int g = b - 8192;
      in  = g < 512 ? wq : (g < 1024 ? wk : wv);
      out = ow + (size_t)(g >> 9) * (DH * DIN);
      i = (size_t)(g & 511) * 256 + threadIdx.x;
    }
    fx4 lo = ((const fx4*)in)[2 * i];
    fx4 hi = ((const fx4*)in)[2 * i + 1];
    bx8 o;
#pragma unroll
    for (int j = 0; j < 4; j++) { o[j] = (__bf16)lo[j]; o[j + 4] = (__bf16)hi[j]; }
    ((bx8*)out)[i] = o;
  } else {
    // mask pack: block g covers 16384 ints; per iter, 256 thr x 8 ints (2x int4)
    const int g = b - 9728;          // 0..1023
    const int tid = threadIdx.x;
#pragma unroll
    for (int i = 0; i < 8; i++) {
      const int4* mp = (const int4*)mask + (((size_t)g * 16384 + (size_t)i * 2048) >> 2) + tid * 2;
      int4 v0 = mp[0], v1 = mp[1];
      unsigned byte = 0;
      byte |= (v0.x != 0);
      byte |= (v0.y != 0) << 1;
      byte |= (v0.z != 0) << 2;
      byte |= (v0.w != 0) << 3;
      byte |= (v1.x != 0) << 4;
      byte |= (v1.y != 0) << 5;
      byte |= (v1.z != 0) << 6;
      byte |= (v1.w != 0) << 7;
      bm[(size_t)g * 2048 + i * 256 + tid] = (u8)byte;
    }
  }
}

// ---------------------------------------------------------------- 128x128 GEMM  C = A @ B^T
// R16: BK=32, LDS 32KB -> 4 blocks/CU (32 waves/CU = max; m97-family occupancy
// mechanism pushed to the limit). 512 thr = 8 waves (2 wr x 4 wc), per-wave
// 64x32, acc[4][2]. 2 bufs x 16KB {A:[128][64B] @0, B:[128][64B] @8192}.
// Swizzle (64B rows, 4 slots): slotb ^= ((row>>1)&3)<<4 -> uniform 2-way bank
// aliasing (free, m136); inverse folded into per-lane global src col.
// Per K-tile: STAGE(t+1) 2 GLD first, 6 ds_read_b128, 8 MFMA, ONE
// vmcnt(0)+barrier. Epilogues/grids identical to R15 (per-wave output
// geometry unchanged).

enum { EP_QKV = 0, EP_EXP = 2, EP_F32 = 3 };

#define GLD(gp, lp)                                                              \
  __builtin_amdgcn_global_load_lds(                                              \
      (const __attribute__((address_space(1))) void*)(const void*)(gp),          \
      (__attribute__((address_space(3))) void*)(void*)(lp), 16, 0, 0)

#define ENDSYNC()                                          \
  do {                                                     \
    asm volatile("s_waitcnt vmcnt(0)" ::: "memory");       \
    __builtin_amdgcn_s_barrier();                          \
    __builtin_amdgcn_sched_barrier(0);                     \
  } while (0)

#define MM(m, n, av, bv) \
  acc[m][n] = __builtin_amdgcn_mfma_f32_16x16x32_bf16(av, bv, acc[m][n], 0, 0, 0)

#define LDA_(bo, m) (*(const bx8*)(aBase + (bo) + (m) * 1024 + cS))
#define LDB_(bo, n) (*(const bx8*)(bBase + (bo) + (n) * 1024 + cS))

#define STAGE(kt, bo) do {                                   \
  GLD(pA + (kt), smem + (bo) + tid * 16);                    \
  GLD(pB + (kt), smem + (bo) + 8192 + tid * 16);             \
} while (0)

template <int EPI>
__global__ __launch_bounds__(512, 8) void gemm128(
    const __bf16* __restrict__ A, const __bf16* __restrict__ Bm,
    void* __restrict__ Cout, void* __restrict__ Cout2,
    const void* __restrict__ Xtra, int N, int K, long sA, long sB) {
  extern __shared__ char smem[];

  int brow, bcol, bz = 0, qrow = 0;
  bool isQ = false;
  if (EPI == EP_QKV) {
    // 1536 blocks: f<512 -> Q (64 row-blocks x 8 col, rows 0-8191);
    // f>=512 -> KV (64 x 16, rows 8192-16383). XCD swizzle chunk = 192.
    int f = (blockIdx.x & 7) * 192 + (blockIdx.x >> 3);
    if (f < 512) {
      isQ = true;
      qrow = (f >> 3) * 128;
      brow = qrow;
      bcol = (f & 7) * 128;
    } else {
      int g = f - 512;
      qrow = (g >> 4) * 128;
      brow = 8192 + qrow;
      bcol = (g & 15) * 128;
    }
  } else {
    // XCD-aware bijective swizzle (pow2 grids, nwg % 8 == 0)
    const unsigned gx = gridDim.x, gy = gridDim.y;
    const unsigned nwg = gx * gy * gridDim.z;
    unsigned flat = (blockIdx.z * gy + blockIdx.y) * gx + blockIdx.x;
    flat = (flat & 7) * (nwg >> 3) + (flat >> 3);
    const int lx = __builtin_ctz(gx), ly = __builtin_ctz(gy);
    brow = ((flat >> lx) & (gy - 1)) * 128;
    bcol = (flat & (gx - 1)) * 128;
    bz   = flat >> (lx + ly);
    A  += (long)bz * sA;
    Bm += (long)bz * sB;
  }

  const int tid  = threadIdx.x;
  const int wid  = tid >> 6;
  const int lane = tid & 63;
  const int wr = wid >> 2;   // 0..1 -> rows wr*64
  const int wc = wid & 3;    // 0..3 -> cols wc*32

  fx4 acc[4][2] = {};

  // staging: thread tid covers LDS bytes [tid*16, tid*16+16) of each 8KB unit
  // (row = tid>>2, phys slot = tid&3); inverse swizzle on global col:
  const int gcol = (((tid & 3) ^ ((tid >> 3) & 3)) << 3);  // elements
  const __bf16* Bsel = (EPI == EP_QKV && !isQ) ? (Bm + (size_t)1048576) : Bm;  // WK after WQ
  const __bf16* pA = A    + (size_t)(brow + (tid >> 2)) * K + gcol;
  const __bf16* pB = Bsel + (size_t)(bcol + (tid >> 2)) * K + gcol;

  // fragment read bases (read-side swizzle: slot ^ ((row>>1)&3)<<4; row bits
  // above frow are multiples of 16 so only frow matters)
  const int frow = lane & 15;
  const int cS   = (((lane >> 4) << 4)) ^ (((frow >> 1) & 3) << 4);
  const char* aBase = smem + (wr * 64 + frow) * 64;
  const char* bBase = smem + 8192 + (wc * 32 + frow) * 64;

  // ---- prologue: stage tile0 into buf0
  STAGE(0, 0);
  ENDSYNC();

  const int nt = K >> 5;
  int cur = 0, nb = 16384;
  bx8 a0, a1, a2, a3, b0, b1;

  for (int t = 0; t < nt; ++t) {
    const int k1 = (t + 1 < nt) ? (t + 1) * 32 : 0;  // junk when past end, never read

    // stage t+1 FIRST: GLD latency hides under ds_read issue + MFMA
    STAGE(k1, nb);

    a0 = LDA_(cur, 0); a1 = LDA_(cur, 1); a2 = LDA_(cur, 2); a3 = LDA_(cur, 3);
    b0 = LDB_(cur, 0); b1 = LDB_(cur, 1);

    __builtin_amdgcn_s_setprio(1);
    MM(0, 0, a0, b0); MM(0, 1, a0, b1);
    MM(1, 0, a1, b0); MM(1, 1, a1, b1);
    MM(2, 0, a2, b0); MM(2, 1, a2, b1);
    MM(3, 0, a3, b0); MM(3, 1, a3, b1);
    __builtin_amdgcn_s_setprio(0);

    ENDSYNC();  // all waves' GLDs for tile t+1 landed; safe to read nb next iter
    int tmp = cur; cur = nb; nb = tmp;
  }

  // ---- epilogue: C/D layout col = lane&15, row = (lane>>4)*4 + j  [verified m89]
  const int r0 = wr * 64 + (lane >> 4) * 4;
  const int c0 = wc * 32 + (lane & 15);

  if (EPI == EP_QKV) {
    if (isQ) {
      __bf16* Cq = (__bf16*)Cout;
#pragma unroll
      for (int m = 0; m < 4; m++) {
        int row = qrow + r0 + m * 16;
#pragma unroll
        for (int n = 0; n < 2; n++) {
          int col = bcol + c0 + n * 16;
#pragma unroll
          for (int j = 0; j < 4; j++)
            Cq[(size_t)(row + j) * 1024 + col] = (__bf16)acc[m][n][j];
        }
      }
    } else if (bcol < 1024) {
      __bf16* Ck = (__bf16*)Cout2;
#pragma unroll
      for (int m = 0; m < 4; m++) {
        int rr = qrow + r0 + m * 16;
#pragma unroll
        for (int n = 0; n < 2; n++) {
          int col = bcol + c0 + n * 16;
#pragma unroll
          for (int j = 0; j < 4; j++)
            Ck[(size_t)(rr + j) * 1024 + col] = (__bf16)acc[m][n][j];
        }
      }
    } else {
      __bf16* Cv = (__bf16*)Xtra;
#pragma unroll
      for (int m = 0; m < 4; m++) {
        int rr = qrow + r0 + m * 16;
        size_t bb = (size_t)(rr >> 11) << 21;  // batch * DH*S
        int sidx = rr & 2047;
#pragma unroll
        for (int n = 0; n < 2; n++) {
          int col = bcol + c0 + n * 16 - 1024;
          bx4 tv;
#pragma unroll
          for (int j = 0; j < 4; j++) tv[j] = (__bf16)acc[m][n][j];
          *(bx4*)&Cv[bb + (size_t)col * S_ + sidx] = tv;
        }
      }
    }
  } else if (EPI == EP_EXP) {
    __bf16* C    = (__bf16*)Cout + (size_t)bz * ((size_t)S_ * S_);
    const u8* Wm = (const u8*)Xtra + (((size_t)bz * S_ * S_) >> 3);
    float csum0 = 0.f, csum1 = 0.f;
#pragma unroll
    for (int m = 0; m < 4; m++) {
      int row = brow + r0 + m * 16;
#pragma unroll
      for (int n = 0; n < 2; n++) {
        int col = bcol + c0 + n * 16;
        float cl = 0.f;
#pragma unroll
        for (int j = 0; j < 4; j++) {
          size_t idx = (size_t)(row + j) * S_ + col;
          bool mk = (Wm[idx >> 3] >> (idx & 7)) & 1;
          float p = mk ? 1.0f : __expf(acc[m][n][j] * 0.03125f);  // 1/sqrt(1024)
          cl += p;
          C[idx] = (__bf16)p;
        }
        if (n == 0) csum0 += cl; else csum1 += cl;
      }
    }
    // fused column-sum: reduce over lane>>4 groups (same col, rows differ)
    csum0 += __shfl_xor(csum0, 16); csum0 += __shfl_xor(csum0, 32);
    csum1 += __shfl_xor(csum1, 16); csum1 += __shfl_xor(csum1, 32);
    if (lane < 16) {
      float* csp = (float*)Cout2 + (size_t)bz * S_ + bcol + wc * 32 + lane;
      atomicAdd(csp, csum0);
      atomicAdd(csp + 16, csum1);
    }
  } else {  // EP_F32
    float* C = (float*)Cout + (size_t)bz * ((size_t)S_ * DH);
#pragma unroll
    for (int m = 0; m < 4; m++) {
      int row = brow + r0 + m * 16;
#pragma unroll
      for (int n = 0; n < 2; n++) {
        int col = bcol + c0 + n * 16;
#pragma unroll
        for (int j = 0; j < 4; j++)
          C[(size_t)(row + j) * N + col] = acc[m][n][j];
      }
    }
  }
}

// ---------------------------------------------------------------- vT[b][h][k] /= colsum[b][k]
__global__ void scale_vt(__bf16* __restrict__ vT, const float* __restrict__ cs) {
  size_t i = (size_t)blockIdx.x * blockDim.x + threadIdx.x;
  size_t e = i * 8;
  int b = (int)(e >> 21);      // DH*S = 2^21 elems per batch
  int k = (int)(e & (S_ - 1)); // contiguous along k
  bx8 v = ((bx8*)vT)[i];
  const float* c = cs + (size_t)b * S_ + k;
#pragma unroll
  for (int j = 0; j < 8; j++) v[j] = (__bf16)((float)v[j] / c[j]);
  ((bx8*)vT)[i] = v;
}

// ---------------------------------------------------------------- launch
extern "C" void kernel_launch(void* const* d_in, const int* in_sizes, int n_in,
                              void* d_out, int out_size, void* d_ws, size_t ws_size,
                              hipStream_t stream) {
  const float* seq1 = (const float*)d_in[0];
  const float* seq2 = (const float*)d_in[1];
  const int*   mask = (const int*)d_in[2];
  const float* Wq   = (const float*)d_in[3];
  const float* Wk   = (const float*)d_in[4];
  const float* Wv   = (const float*)d_in[5];

  char* ws = (char*)d_ws;
  __bf16* A1  = (__bf16*)(ws + WS_A1);   // stacked [seq1;seq2] 16384x1024
  __bf16* A2  = (__bf16*)(ws + WS_A2);
  __bf16* Pu  = (__bf16*)(ws + WS_PU);
  __bf16* WQb = (__bf16*)(ws + WS_WQ);   // WQ,WK,WV contiguous 3072x1024
  u8*     bm  = (u8*)(ws + WS_BM);
  __bf16* qb  = (__bf16*)(ws + WS_Q);
  __bf16* kb  = (__bf16*)(ws + WS_K);
  __bf16* vTb = (__bf16*)(ws + WS_VT);
  float*  cs  = (float*)(ws + WS_CS);

  (void)hipFuncSetAttribute((const void*)gemm128<EP_QKV>,
      hipFuncAttributeMaxDynamicSharedMemorySize, 32768);
  (void)hipFuncSetAttribute((const void*)gemm128<EP_EXP>,
      hipFuncAttributeMaxDynamicSharedMemorySize, 32768);
  (void)hipFuncSetAttribute((const void*)gemm128<EP_F32>,
      hipFuncAttributeMaxDynamicSharedMemorySize, 32768);

  // fused prep: seq cvt + weight cvt + vectorized mask pack + cs zero
  prep<<<10753, 256, 0, stream>>>(seq1, seq2, Wq, Wk, Wv, mask, A1, A2, WQb, bm, cs);

  // fused q/k/vT projections: 1536 blocks (now up to 4 blocks/CU resident)
  gemm128<EP_QKV><<<1536, 512, 32768, stream>>>(
      A1, WQb, qb, kb, vTb, 0, DIN, 0, 0);

  // Pu[b,q,k] = mask ? 1 : exp(q.k/32); fused column-sum into cs — 1024 blocks
  gemm128<EP_EXP><<<dim3(S_ / 128, S_ / 128, B_), 512, 32768, stream>>>(
      qb, kb, Pu, cs, bm, S_, DH, (long)S_ * DH, (long)S_ * DH);

  // fold 1/colsum into vT
  scale_vt<<<(B_ * DH * S_ / 8) / 256, 256, 0, stream>>>(vTb, cs);

  // out[b,q,h] = sum_k Pu[b,q,k] * vT'[b,h,k]  — 512 blocks
  gemm128<EP_F32><<<dim3(DH / 128, S_ / 128, B_), 512, 32768, stream>>>(
      Pu, vTb, (float*)d_out, nullptr, nullptr, DH, S_, (long)S_ * S_, (long)DH * S_);
}

// Round 17
// 162.345 us; speedup vs baseline: 1.2280x; 1.2280x over previous
//
#include <hip/hip_runtime.h>

typedef __bf16 bx8 __attribute__((ext_vector_type(8)));
typedef __bf16 bx4 __attribute__((ext_vector_type(4)));
typedef float  fx4 __attribute__((ext_vector_type(4)));
typedef unsigned long long u64;
typedef unsigned char u8;

#define B_   4
#define S_   2048
#define DIN  1024
#define DH   1024

#define MB ((size_t)1 << 20)
// workspace layout (bytes)
#define WS_A1 ((size_t)0)          // seq1 bf16, 16MB  (stacked with A2; aliased by Pu later)
#define WS_A2 ((size_t)16*MB)      // seq2 bf16, 16MB  (A1..A2 contiguous = 16384x1024)
#define WS_PU ((size_t)0)          // exp-scores bf16, 32MB (after QKV done)
#define WS_WQ ((size_t)32*MB)      // WQ,WK,WV bf16 contiguous 3072x1024 (6MB)
#define WS_BM ((size_t)38*MB)      // mask bitmask 2MB (bytes: bit j of byte i = mask[8i+j])
#define WS_Q  ((size_t)40*MB)      // q bf16 [B*S, DH] 16MB
#define WS_K  ((size_t)56*MB)      // k bf16 [B*S, DH] 16MB
#define WS_VT ((size_t)72*MB)      // v^T bf16 [B, DH, S] 16MB
#define WS_CS ((size_t)88*MB)      // colsum fp32 [B, S] 32KB

// ---------------------------------------------------------------- fused prep:
// blocks [0,8192): seq1/seq2 f32->bf16; [8192,9728): Wq/Wk/Wv f32->bf16;
// [9728,10752): mask int32 -> byte-bitmask (32B/lane loads, 1B/lane stores);
// block 10752: zero cs. All branching is block-uniform.
__global__ void prep(const float* __restrict__ s1, const float* __restrict__ s2,
                     const float* __restrict__ wq, const float* __restrict__ wk,
                     const float* __restrict__ wv, const int* __restrict__ mask,
                     __bf16* __restrict__ o1, __bf16* __restrict__ o2,
                     __bf16* __restrict__ ow, u8* __restrict__ bm,
                     float* __restrict__ cs) {
  const int b = blockIdx.x;
  if (b >= 10752) {
#pragma unroll
    for (int j = 0; j < 8; j++)
      ((fx4*)cs)[threadIdx.x * 8 + j] = fx4{0.f, 0.f, 0.f, 0.f};
    return;
  }
  if (b < 9728) {
    const float* in;
    __bf16* out;
    size_t i;
    if (b < 8192) {
      in  = b < 4096 ? s1 : s2;
      out = b < 4096 ? o1 : o2;
      i = (size_t)(b & 4095) * 256 + threadIdx.x;
    } else {
      int g = b - 8192;
      in  = g < 512 ? wq : (g < 1024 ? wk : wv);
      out = ow + (size_t)(g >> 9) * (DH * DIN);
      i = (size_t)(g & 511) * 256 + threadIdx.x;
    }
    fx4 lo = ((const fx4*)in)[2 * i];
    fx4 hi = ((const fx4*)in)[2 * i + 1];
    bx8 o;
#pragma unroll
    for (int j = 0; j < 4; j++) { o[j] = (__bf16)lo[j]; o[j + 4] = (__bf16)hi[j]; }
    ((bx8*)out)[i] = o;
  } else {
    // mask pack: block g covers 16384 ints; per iter, 256 thr x 8 ints (2x int4)
    const int g = b - 9728;          // 0..1023
    const int tid = threadIdx.x;
#pragma unroll
    for (int i = 0; i < 8; i++) {
      const int4* mp = (const int4*)mask + (((size_t)g * 16384 + (size_t)i * 2048) >> 2) + tid * 2;
      int4 v0 = mp[0], v1 = mp[1];
      unsigned byte = 0;
      byte |= (v0.x != 0);
      byte |= (v0.y != 0) << 1;
      byte |= (v0.z != 0) << 2;
      byte |= (v0.w != 0) << 3;
      byte |= (v1.x != 0) << 4;
      byte |= (v1.y != 0) << 5;
      byte |= (v1.z != 0) << 6;
      byte |= (v1.w != 0) << 7;
      bm[(size_t)g * 2048 + i * 256 + tid] = (u8)byte;
    }
  }
}

// ---------------------------------------------------------------- 128x128 GEMM  C = A @ B^T
// R15-proven config (measured best, 163.5us total): BM=BN=128, BK=64,
// 512 thr = 8 waves (2 wr x 4 wc), per-wave 64x32, acc[4][2]. LDS 64KB ->
// 2 blocks/CU (m97/m114 occupancy-overlap). 2 bufs x 32KB {A:[128][128B] @0,
// B @16384}. Swizzle: colb ^= (row&7)<<4, inverse folded into per-lane global
// src. Per K-tile: stage t+1 FIRST (GLD latency hides under ds_read+MFMA),
// then 12 ds_read_b128 + 16 MFMA, ONE vmcnt(0)+barrier at tile end.
// EXP epilogue fuses column-sum atomics (replaces 32MB colsum pass).
// Family sweep complete: 1 blk/CU mega-tiles (R2-R7) worse; 4 blk/CU BK=32
// (R16) worse (2x sync count, MfmaUtil 35->27). 2 blk/CU BK=64 is optimal.
// R14 lesson: no BW co-dispatch into these grids (breaks XCD-swizzle L2
// co-residency: FETCH 62->235MB).

enum { EP_QKV = 0, EP_EXP = 2, EP_F32 = 3 };

#define GLD(gp, lp)                                                              \
  __builtin_amdgcn_global_load_lds(                                              \
      (const __attribute__((address_space(1))) void*)(const void*)(gp),          \
      (__attribute__((address_space(3))) void*)(void*)(lp), 16, 0, 0)

#define ENDSYNC()                                          \
  do {                                                     \
    asm volatile("s_waitcnt vmcnt(0)" ::: "memory");       \
    __builtin_amdgcn_s_barrier();                          \
    __builtin_amdgcn_sched_barrier(0);                     \
  } while (0)

#define MM(m, n, av, bv) \
  acc[m][n] = __builtin_amdgcn_mfma_f32_16x16x32_bf16(av, bv, acc[m][n], 0, 0, 0)

#define LDA_(bo, m, kk) (*(const bx8*)(aBase + (bo) + (m) * 2048 + ((kk) ? c1s : c0s)))
#define LDB_(bo, n, kk) (*(const bx8*)(bBase + (bo) + (n) * 2048 + ((kk) ? c1s : c0s)))

#define STAGE_A(kt, bo) do {                                              \
  GLD(pA + (kt),                    smem + (bo) + tid * 16);              \
  GLD(pA + (size_t)64 * K + (kt),   smem + (bo) + 8192 + tid * 16);       \
} while (0)
#define STAGE_B(kt, bo) do {                                              \
  GLD(pB + (kt),                    smem + (bo) + 16384 + tid * 16);      \
  GLD(pB + (size_t)64 * K + (kt),   smem + (bo) + 24576 + tid * 16);      \
} while (0)

template <int EPI>
__global__ __launch_bounds__(512, 4) void gemm128(
    const __bf16* __restrict__ A, const __bf16* __restrict__ Bm,
    void* __restrict__ Cout, void* __restrict__ Cout2,
    const void* __restrict__ Xtra, int N, int K, long sA, long sB) {
  extern __shared__ char smem[];

  int brow, bcol, bz = 0, qrow = 0;
  bool isQ = false;
  if (EPI == EP_QKV) {
    // 1536 blocks: f<512 -> Q (64 row-blocks x 8 col, rows 0-8191);
    // f>=512 -> KV (64 x 16, rows 8192-16383). XCD swizzle chunk = 192.
    int f = (blockIdx.x & 7) * 192 + (blockIdx.x >> 3);
    if (f < 512) {
      isQ = true;
      qrow = (f >> 3) * 128;
      brow = qrow;
      bcol = (f & 7) * 128;
    } else {
      int g = f - 512;
      qrow = (g >> 4) * 128;
      brow = 8192 + qrow;
      bcol = (g & 15) * 128;
    }
  } else {
    // XCD-aware bijective swizzle (pow2 grids, nwg % 8 == 0)
    const unsigned gx = gridDim.x, gy = gridDim.y;
    const unsigned nwg = gx * gy * gridDim.z;
    unsigned flat = (blockIdx.z * gy + blockIdx.y) * gx + blockIdx.x;
    flat = (flat & 7) * (nwg >> 3) + (flat >> 3);
    const int lx = __builtin_ctz(gx), ly = __builtin_ctz(gy);
    brow = ((flat >> lx) & (gy - 1)) * 128;
    bcol = (flat & (gx - 1)) * 128;
    bz   = flat >> (lx + ly);
    A  += (long)bz * sA;
    Bm += (long)bz * sB;
  }

  const int tid  = threadIdx.x;
  const int wid  = tid >> 6;
  const int lane = tid & 63;
  const int wr = wid >> 2;   // 0..1 -> rows wr*64
  const int wc = wid & 3;    // 0..3 -> cols wc*32

  fx4 acc[4][2] = {};

  // staging: thread covers lds flat tid*16 per 8KB unit; inverse swizzle on global col
  const int gcol = (((tid & 7) ^ ((tid >> 3) & 7)) << 3);  // elements
  const __bf16* Bsel = (EPI == EP_QKV && !isQ) ? (Bm + (size_t)1048576) : Bm;  // WK after WQ
  const __bf16* pA = A    + (size_t)(brow + (tid >> 3)) * K + gcol;
  const __bf16* pB = Bsel + (size_t)(bcol + (tid >> 3)) * K + gcol;

  // fragment read bases (read-side swizzle)
  const int frow = lane & 15;
  const int slot = (lane >> 4) << 4;
  const int c0s  = slot ^ ((frow & 7) << 4);
  const int c1s  = (64 + slot) ^ ((frow & 7) << 4);
  const char* aBase = smem + (wr * 64 + frow) * 128;
  const char* bBase = smem + 16384 + (wc * 32 + frow) * 128;

  // ---- prologue: stage tile0 into buf0
  STAGE_A(0, 0); STAGE_B(0, 0);
  ENDSYNC();

  const int nt = K >> 6;
  int cur = 0, nb = 32768;
  bx8 a00, a01, a02, a03, a10, a11, a12, a13, b00, b01, b10, b11;

  for (int t = 0; t < nt; ++t) {
    const int k1 = (t + 1 < nt) ? (t + 1) * 64 : 0;  // junk when past end, never read

    // stage t+1 FIRST: GLD latency hides under ds_read issue + MFMA
    STAGE_A(k1, nb); STAGE_B(k1, nb);

    a00 = LDA_(cur, 0, 0); a01 = LDA_(cur, 1, 0); a02 = LDA_(cur, 2, 0); a03 = LDA_(cur, 3, 0);
    b00 = LDB_(cur, 0, 0); b01 = LDB_(cur, 1, 0);
    a10 = LDA_(cur, 0, 1); a11 = LDA_(cur, 1, 1); a12 = LDA_(cur, 2, 1); a13 = LDA_(cur, 3, 1);
    b10 = LDB_(cur, 0, 1); b11 = LDB_(cur, 1, 1);

    __builtin_amdgcn_s_setprio(1);
    MM(0, 0, a00, b00); MM(0, 1, a00, b01);
    MM(1, 0, a01, b00); MM(1, 1, a01, b01);
    MM(2, 0, a02, b00); MM(2, 1, a02, b01);
    MM(3, 0, a03, b00); MM(3, 1, a03, b01);
    MM(0, 0, a10, b10); MM(0, 1, a10, b11);
    MM(1, 0, a11, b10); MM(1, 1, a11, b11);
    MM(2, 0, a12, b10); MM(2, 1, a12, b11);
    MM(3, 0, a13, b10); MM(3, 1, a13, b11);
    __builtin_amdgcn_s_setprio(0);

    ENDSYNC();  // all waves' GLDs for tile t+1 landed; safe to read nb next iter
    int tmp = cur; cur = nb; nb = tmp;
  }

  // ---- epilogue: C/D layout col = lane&15, row = (lane>>4)*4 + j  [verified m89]
  const int r0 = wr * 64 + (lane >> 4) * 4;
  const int c0 = wc * 32 + (lane & 15);

  if (EPI == EP_QKV) {
    if (isQ) {
      __bf16* Cq = (__bf16*)Cout;
#pragma unroll
      for (int m = 0; m < 4; m++) {
        int row = qrow + r0 + m * 16;
#pragma unroll
        for (int n = 0; n < 2; n++) {
          int col = bcol + c0 + n * 16;
#pragma unroll
          for (int j = 0; j < 4; j++)
            Cq[(size_t)(row + j) * 1024 + col] = (__bf16)acc[m][n][j];
        }
      }
    } else if (bcol < 1024) {
      __bf16* Ck = (__bf16*)Cout2;
#pragma unroll
      for (int m = 0; m < 4; m++) {
        int rr = qrow + r0 + m * 16;
#pragma unroll
        for (int n = 0; n < 2; n++) {
          int col = bcol + c0 + n * 16;
#pragma unroll
          for (int j = 0; j < 4; j++)
            Ck[(size_t)(rr + j) * 1024 + col] = (__bf16)acc[m][n][j];
        }
      }
    } else {
      __bf16* Cv = (__bf16*)Xtra;
#pragma unroll
      for (int m = 0; m < 4; m++) {
        int rr = qrow + r0 + m * 16;
        size_t bb = (size_t)(rr >> 11) << 21;  // batch * DH*S
        int sidx = rr & 2047;
#pragma unroll
        for (int n = 0; n < 2; n++) {
          int col = bcol + c0 + n * 16 - 1024;
          bx4 tv;
#pragma unroll
          for (int j = 0; j < 4; j++) tv[j] = (__bf16)acc[m][n][j];
          *(bx4*)&Cv[bb + (size_t)col * S_ + sidx] = tv;
        }
      }
    }
  } else if (EPI == EP_EXP) {
    __bf16* C    = (__bf16*)Cout + (size_t)bz * ((size_t)S_ * S_);
    const u8* Wm = (const u8*)Xtra + (((size_t)bz * S_ * S_) >> 3);
    float csum0 = 0.f, csum1 = 0.f;
#pragma unroll
    for (int m = 0; m < 4; m++) {
      int row = brow + r0 + m * 16;
#pragma unroll
      for (int n = 0; n < 2; n++) {
        int col = bcol + c0 + n * 16;
        float cl = 0.f;
#pragma unroll
        for (int j = 0; j < 4; j++) {
          size_t idx = (size_t)(row + j) * S_ + col;
          bool mk = (Wm[idx >> 3] >> (idx & 7)) & 1;
          float p = mk ? 1.0f : __expf(acc[m][n][j] * 0.03125f);  // 1/sqrt(1024)
          cl += p;
          C[idx] = (__bf16)p;
        }
        if (n == 0) csum0 += cl; else csum1 += cl;
      }
    }
    // fused column-sum: reduce over lane>>4 groups (same col, rows differ)
    csum0 += __shfl_xor(csum0, 16); csum0 += __shfl_xor(csum0, 32);
    csum1 += __shfl_xor(csum1, 16); csum1 += __shfl_xor(csum1, 32);
    if (lane < 16) {
      float* csp = (float*)Cout2 + (size_t)bz * S_ + bcol + wc * 32 + lane;
      atomicAdd(csp, csum0);
      atomicAdd(csp + 16, csum1);
    }
  } else {  // EP_F32
    float* C = (float*)Cout + (size_t)bz * ((size_t)S_ * DH);
#pragma unroll
    for (int m = 0; m < 4; m++) {
      int row = brow + r0 + m * 16;
#pragma unroll
      for (int n = 0; n < 2; n++) {
        int col = bcol + c0 + n * 16;
#pragma unroll
        for (int j = 0; j < 4; j++)
          C[(size_t)(row + j) * N + col] = acc[m][n][j];
      }
    }
  }
}

// ---------------------------------------------------------------- vT[b][h][k] /= colsum[b][k]
__global__ void scale_vt(__bf16* __restrict__ vT, const float* __restrict__ cs) {
  size_t i = (size_t)blockIdx.x * blockDim.x + threadIdx.x;
  size_t e = i * 8;
  int b = (int)(e >> 21);      // DH*S = 2^21 elems per batch
  int k = (int)(e & (S_ - 1)); // contiguous along k
  bx8 v = ((bx8*)vT)[i];
  const float* c = cs + (size_t)b * S_ + k;
#pragma unroll
  for (int j = 0; j < 8; j++) v[j] = (__bf16)((float)v[j] / c[j]);
  ((bx8*)vT)[i] = v;
}

// ---------------------------------------------------------------- launch
extern "C" void kernel_launch(void* const* d_in, const int* in_sizes, int n_in,
                              void* d_out, int out_size, void* d_ws, size_t ws_size,
                              hipStream_t stream) {
  const float* seq1 = (const float*)d_in[0];
  const float* seq2 = (const float*)d_in[1];
  const int*   mask = (const int*)d_in[2];
  const float* Wq   = (const float*)d_in[3];
  const float* Wk   = (const float*)d_in[4];
  const float* Wv   = (const float*)d_in[5];

  char* ws = (char*)d_ws;
  __bf16* A1  = (__bf16*)(ws + WS_A1);   // stacked [seq1;seq2] 16384x1024
  __bf16* A2  = (__bf16*)(ws + WS_A2);
  __bf16* Pu  = (__bf16*)(ws + WS_PU);
  __bf16* WQb = (__bf16*)(ws + WS_WQ);   // WQ,WK,WV contiguous 3072x1024
  u8*     bm  = (u8*)(ws + WS_BM);
  __bf16* qb  = (__bf16*)(ws + WS_Q);
  __bf16* kb  = (__bf16*)(ws + WS_K);
  __bf16* vTb = (__bf16*)(ws + WS_VT);
  float*  cs  = (float*)(ws + WS_CS);

  (void)hipFuncSetAttribute((const void*)gemm128<EP_QKV>,
      hipFuncAttributeMaxDynamicSharedMemorySize, 65536);
  (void)hipFuncSetAttribute((const void*)gemm128<EP_EXP>,
      hipFuncAttributeMaxDynamicSharedMemorySize, 65536);
  (void)hipFuncSetAttribute((const void*)gemm128<EP_F32>,
      hipFuncAttributeMaxDynamicSharedMemorySize, 65536);

  // fused prep: seq cvt + weight cvt + vectorized mask pack + cs zero
  prep<<<10753, 256, 0, stream>>>(seq1, seq2, Wq, Wk, Wv, mask, A1, A2, WQb, bm, cs);

  // fused q/k/vT projections: 1536 balanced blocks (3 rounds at 2 blocks/CU)
  gemm128<EP_QKV><<<1536, 512, 65536, stream>>>(
      A1, WQb, qb, kb, vTb, 0, DIN, 0, 0);

  // Pu[b,q,k] = mask ? 1 : exp(q.k/32); fused column-sum into cs — 1024 blocks
  gemm128<EP_EXP><<<dim3(S_ / 128, S_ / 128, B_), 512, 65536, stream>>>(
      qb, kb, Pu, cs, bm, S_, DH, (long)S_ * DH, (long)S_ * DH);

  // fold 1/colsum into vT
  scale_vt<<<(B_ * DH * S_ / 8) / 256, 256, 0, stream>>>(vTb, cs);

  // out[b,q,h] = sum_k Pu[b,q,k] * vT'[b,h,k]  — 512 blocks (1 round)
  gemm128<EP_F32><<<dim3(DH / 128, S_ / 128, B_), 512, 65536, stream>>>(
      Pu, vTb, (float*)d_out, nullptr, nullptr, DH, S_, (long)S_ * S_, (long)DH * S_);
}